// Round 1
// 3292.538 us; speedup vs baseline: 1.1402x; 1.1402x over previous
//
#include <hip/hip_runtime.h>
#include <hip/hip_bf16.h>
#include <math.h>

// GPT forward: L=6, D=1024, H=16, HD=64, T=1024, B=2, V=50257
// All GEMMs: bf16 inputs, fp32 MFMA accumulate. Residual stream fp32.

using u16 = unsigned short;
typedef __attribute__((ext_vector_type(4))) float f32x4;
typedef __attribute__((ext_vector_type(8))) short s16x8;

static __device__ __forceinline__ u16 f2b(float f) {
    __hip_bfloat16 h = __float2bfloat16(f);
    return *reinterpret_cast<u16*>(&h);
}
static __device__ __forceinline__ float b2f(u16 u) {
    __hip_bfloat16 h = *reinterpret_cast<__hip_bfloat16*>(&u);
    return __bfloat162float(h);
}

// Async global->LDS, 16B per lane. LDS dest is wave-uniform base + lane*16.
#define GLDS16(gp, lp) __builtin_amdgcn_global_load_lds( \
    (const __attribute__((address_space(1))) unsigned int*)(gp), \
    (__attribute__((address_space(3))) unsigned int*)(lp), 16, 0, 0)

// ---------------------------------------------------------------------------
// Generic GEMM: C[M,N] = scale * A[M,K] @ B[K,N] (+bias) (+gelu) (+resid)
// A row-major bf16 (lda), Bt = B^T row-major bf16 [N,K] (ldb).
// z-batching: offsets = (z/ZH)*Outer + (z%ZH)*Inner for A, B, C.
// flags: 1 = bf16 output (Cb), else fp32 (Cf); 2 = exact GELU.
// Block tile 128x128, BK=32, 4 waves each 64x64 via 4x4 mfma 16x16x32.
// Grid: x = M-blocks (fast), y = N-blocks — column-major dispatch so the
// concurrent-block window reuses each B panel across all M-blocks (L2/L3).
// Staging via global_load_lds width=16 (no VGPR round-trip); ragged N is
// handled by clamping the source row (duplicate reads; cols>=N never stored).
// ---------------------------------------------------------------------------
__global__ __launch_bounds__(256) void gemm_bt(
    const u16* __restrict__ A, const u16* __restrict__ Bt,
    float* __restrict__ Cf, u16* __restrict__ Cb,
    const float* __restrict__ bias, const float* __restrict__ resid,
    int M, int N, int K, int lda, int ldb, int ldc,
    long long aO, long long aI, long long bO, long long bI,
    long long cO, long long cI, int ZH, float scale, int flags)
{
    __shared__ u16 As[128 * 32];
    __shared__ u16 Bs[128 * 32];

    const int t = threadIdx.x;
    const int lane = t & 63, wave = t >> 6;
    const int wm = wave >> 1, wn = wave & 1;
    const int lr = lane & 15, lq = lane >> 4;
    const int m0 = blockIdx.x * 128;
    const int n0 = blockIdx.y * 128;
    const int zb = blockIdx.z / ZH, zh = blockIdx.z % ZH;
    const long long offA = (long long)zb * aO + (long long)zh * aI;
    const long long offB = (long long)zb * bO + (long long)zh * bI;
    const long long offC = (long long)zb * cO + (long long)zh * cI;

    f32x4 acc[4][4];
#pragma unroll
    for (int i = 0; i < 4; i++)
#pragma unroll
        for (int j = 0; j < 4; j++) acc[i][j] = (f32x4){0.f, 0.f, 0.f, 0.f};

    // staging map: thread t covers row r0 = t/4, k-chunk kk0 = (t%4)*8
    // -> LDS byte offset t*16 (linear), i.e. wave base = wave*1024.
    const int r0 = t >> 2;
    const int kk0 = (t & 3) << 3;
    const int wvb = wave << 10;

    for (int k0 = 0; k0 < K; k0 += 32) {
        __syncthreads();
        {   // stage A tile 128x32 (M always multiple of 128)
            const u16* ap = A + offA + (size_t)(m0 + r0) * lda + (k0 + kk0);
            GLDS16(ap, (char*)As + wvb);
            GLDS16(ap + (size_t)64 * lda, (char*)As + 4096 + wvb);
        }
        {   // stage Bt tile 128x32 (rows are N-dim; clamp ragged edge)
            int nr  = n0 + r0;      if (nr  >= N) nr  = N - 1;
            int nr2 = n0 + r0 + 64; if (nr2 >= N) nr2 = N - 1;
            const u16* bp  = Bt + offB + (size_t)nr  * ldb + (k0 + kk0);
            const u16* bp2 = Bt + offB + (size_t)nr2 * ldb + (k0 + kk0);
            GLDS16(bp,  (char*)Bs + wvb);
            GLDS16(bp2, (char*)Bs + 4096 + wvb);
        }
        __syncthreads();

        s16x8 a[4], b[4];
#pragma unroll
        for (int i = 0; i < 4; i++)
            a[i] = *(const s16x8*)&As[(wm * 64 + i * 16 + lr) * 32 + lq * 8];
#pragma unroll
        for (int j = 0; j < 4; j++)
            b[j] = *(const s16x8*)&Bs[(wn * 64 + j * 16 + lr) * 32 + lq * 8];
#pragma unroll
        for (int i = 0; i < 4; i++)
#pragma unroll
            for (int j = 0; j < 4; j++)
                acc[i][j] = __builtin_amdgcn_mfma_f32_16x16x32_bf16(
                    a[i], b[j], acc[i][j], 0, 0, 0);
    }

    const bool obf = (flags & 1) != 0;
    const bool gel = (flags & 2) != 0;
#pragma unroll
    for (int i = 0; i < 4; i++) {
#pragma unroll
        for (int j = 0; j < 4; j++) {
            int col = n0 + wn * 64 + j * 16 + lr;
            if (col >= N) continue;
#pragma unroll
            for (int r = 0; r < 4; r++) {
                int row = m0 + wm * 64 + i * 16 + lq * 4 + r;
                float v = acc[i][j][r] * scale;
                if (bias) v += bias[col];
                if (gel) v = 0.5f * v * (1.f + erff(v * 0.70710678118f));
                long long ci = offC + (long long)row * ldc + col;
                if (resid) v += resid[ci];
                if (obf) Cb[ci] = f2b(v);
                else     Cf[ci] = v;
            }
        }
    }
}

// ---------------------------------------------------------------------------
// Transpose + convert to bf16: out[c*ldo + r] = in[r*ldi + c]. R,C mult of 32.
// ---------------------------------------------------------------------------
__global__ __launch_bounds__(256) void transpose_conv(
    const void* __restrict__ in, u16* __restrict__ out,
    int R, int C, int ldi, int ldo, long long zi, long long zo, int in_bf16)
{
    __shared__ float tile[32][33];
    int tx = threadIdx.x & 31, ty = threadIdx.x >> 5;  // 32x8
    int r0 = blockIdx.y * 32, c0 = blockIdx.x * 32;
    long long ioff = (long long)blockIdx.z * zi;
    long long ooff = (long long)blockIdx.z * zo;
#pragma unroll
    for (int i = 0; i < 32; i += 8) {
        long long r = r0 + ty + i, c = c0 + tx;
        float v;
        if (in_bf16) v = b2f(((const u16*)in)[ioff + r * ldi + c]);
        else         v = ((const float*)in)[ioff + r * ldi + c];
        tile[ty + i][tx] = v;
    }
    __syncthreads();
#pragma unroll
    for (int i = 0; i < 32; i += 8) {
        long long c = c0 + ty + i, r = r0 + tx;
        out[ooff + c * ldo + r] = f2b(tile[tx][ty + i]);
    }
}

// flat fp32 -> bf16 (n multiple of 4)
__global__ __launch_bounds__(256) void conv_f2b(
    const float* __restrict__ in, u16* __restrict__ out, size_t n)
{
    size_t i = ((size_t)blockIdx.x * 256 + threadIdx.x) * 4;
    if (i >= n) return;
    float4 f = *(const float4*)&in[i];
    out[i + 0] = f2b(f.x);
    out[i + 1] = f2b(f.y);
    out[i + 2] = f2b(f.z);
    out[i + 3] = f2b(f.w);
}

// x[row,:] = tok_W[idx[row],:] + pos_W[row&1023,:]
__global__ __launch_bounds__(256) void embed_k(
    const int* __restrict__ idx, const float* __restrict__ tokW,
    const float* __restrict__ posW, float* __restrict__ x)
{
    int row = blockIdx.x;
    int tt = row & 1023;
    int tok = idx[row];
    int c = threadIdx.x * 4;
    float4 a = *(const float4*)&tokW[(size_t)tok * 1024 + c];
    float4 p = *(const float4*)&posW[(size_t)tt * 1024 + c];
    float4 r = {a.x + p.x, a.y + p.y, a.z + p.z, a.w + p.w};
    *(float4*)&x[(size_t)row * 1024 + c] = r;
}

// LayerNorm over D=1024, fp32 in, bf16 out. One block per row.
__global__ __launch_bounds__(256) void ln_k(
    const float* __restrict__ x, const float* __restrict__ g,
    const float* __restrict__ b, u16* __restrict__ out)
{
    __shared__ float sbuf[8];
    int row = blockIdx.x;
    int c = threadIdx.x * 4;
    float4 v = *(const float4*)&x[(size_t)row * 1024 + c];
    float s = v.x + v.y + v.z + v.w;
    float s2 = v.x * v.x + v.y * v.y + v.z * v.z + v.w * v.w;
#pragma unroll
    for (int o = 32; o > 0; o >>= 1) {
        s += __shfl_down(s, o, 64);
        s2 += __shfl_down(s2, o, 64);
    }
    int lane = threadIdx.x & 63, wave = threadIdx.x >> 6;
    if (lane == 0) { sbuf[wave] = s; sbuf[4 + wave] = s2; }
    __syncthreads();
    float mean = (sbuf[0] + sbuf[1] + sbuf[2] + sbuf[3]) * (1.f / 1024.f);
    float m2 = (sbuf[4] + sbuf[5] + sbuf[6] + sbuf[7]) * (1.f / 1024.f);
    float rstd = rsqrtf(m2 - mean * mean + 1e-5f);
    float vals[4] = {v.x, v.y, v.z, v.w};
    u16 o4[4];
#pragma unroll
    for (int i = 0; i < 4; i++) {
        float y = (vals[i] - mean) * rstd * g[c + i] + b[c + i];
        o4[i] = f2b(y);
    }
    *(uint2*)&out[(size_t)row * 1024 + c] = *(uint2*)o4;
}

// Causal softmax over rows of S [32*1024, 1024] bf16, in-place -> P.
// row = bh*1024 + q; valid keys k <= q; invalid entries written as 0.
__global__ __launch_bounds__(256) void softmax_causal(u16* __restrict__ S)
{
    __shared__ float sbuf[8];
    int row = blockIdx.x;
    int q = row & 1023;
    u16* p = S + (size_t)row * 1024;
    int c = threadIdx.x * 4;
    u16 u4[4];
    *(uint2*)u4 = *(const uint2*)&p[c];
    float v[4];
#pragma unroll
    for (int i = 0; i < 4; i++) v[i] = (c + i <= q) ? b2f(u4[i]) : -1e30f;
    float mx = fmaxf(fmaxf(v[0], v[1]), fmaxf(v[2], v[3]));
#pragma unroll
    for (int o = 32; o > 0; o >>= 1) mx = fmaxf(mx, __shfl_down(mx, o, 64));
    int lane = threadIdx.x & 63, wave = threadIdx.x >> 6;
    if (lane == 0) sbuf[wave] = mx;
    __syncthreads();
    mx = fmaxf(fmaxf(sbuf[0], sbuf[1]), fmaxf(sbuf[2], sbuf[3]));
    float e[4], sum = 0.f;
#pragma unroll
    for (int i = 0; i < 4; i++) {
        e[i] = (c + i <= q) ? expf(v[i] - mx) : 0.f;
        sum += e[i];
    }
#pragma unroll
    for (int o = 32; o > 0; o >>= 1) sum += __shfl_down(sum, o, 64);
    if (lane == 0) sbuf[4 + wave] = sum;
    __syncthreads();
    float inv = 1.f / (sbuf[4] + sbuf[5] + sbuf[6] + sbuf[7]);
#pragma unroll
    for (int i = 0; i < 4; i++) u4[i] = f2b(e[i] * inv);
    *(uint2*)&p[c] = *(uint2*)u4;
}

// ---------------------------------------------------------------------------
extern "C" void kernel_launch(void* const* d_in, const int* in_sizes, int n_in,
                              void* d_out, int out_size, void* d_ws, size_t ws_size,
                              hipStream_t stream)
{
    const int*   idx  = (const int*)d_in[0];
    const float* tokW = (const float*)d_in[1];
    const float* posW = (const float*)d_in[2];
    const float* ln1g = (const float*)d_in[3];
    const float* ln1b = (const float*)d_in[4];
    const float* Wq   = (const float*)d_in[5];
    const float* Wk   = (const float*)d_in[6];
    const float* Wv   = (const float*)d_in[7];
    const float* Wo   = (const float*)d_in[8];
    const float* bo   = (const float*)d_in[9];
    const float* ln2g = (const float*)d_in[10];
    const float* ln2b = (const float*)d_in[11];
    const float* W1   = (const float*)d_in[12];
    const float* b1   = (const float*)d_in[13];
    const float* W2   = (const float*)d_in[14];
    const float* b2   = (const float*)d_in[15];
    const float* lnfg = (const float*)d_in[16];
    const float* lnfb = (const float*)d_in[17];
    float* out = (float*)d_out;

    char* w = (char*)d_ws;
    auto alloc = [&](size_t bytes) -> char* {
        char* p = w;
        w += (bytes + 255) & ~(size_t)255;
        return p;
    };
    float* x    = (float*)alloc(2048ull * 1024 * 4);   // residual stream fp32
    u16* h      = (u16*)alloc(2048ull * 1024 * 2);     // LN out bf16
    u16* qkv    = (u16*)alloc(2048ull * 3072 * 2);     // fused QKV out
    u16* vt     = (u16*)alloc(2ull * 1024 * 1024 * 2); // V transposed per batch
    u16* attb   = (u16*)alloc(2048ull * 1024 * 2);     // attention out bf16
    u16* ffb    = (u16*)alloc(2048ull * 4096 * 2);     // FF hidden bf16
    u16* wqkvT  = (u16*)alloc(3072ull * 1024 * 2);     // per-layer Wqkv^T bf16
    u16* woT    = (u16*)alloc(1024ull * 1024 * 2);
    u16* w1T    = (u16*)alloc(4096ull * 1024 * 2);
    u16* w2T    = (u16*)alloc(1024ull * 4096 * 2);
    u16* S      = (u16*)alloc(50257ull * 1024 * 2);    // scores/P; reused as tok_W bf16
    u16* twb    = S;

    auto gemm = [&](const u16* A, const u16* Bt, float* Cf, u16* Cb,
                    const float* bias, const float* resid,
                    int M, int N, int K, int lda, int ldb, int ldc,
                    long long aO, long long aI, long long bO, long long bI,
                    long long cO, long long cI, int Z, int ZH,
                    float scale, int flags) {
        // x = M-blocks (fast-varying), y = N-blocks -> column-major dispatch
        dim3 g(M / 128, (N + 127) / 128, Z);
        gemm_bt<<<g, dim3(256), 0, stream>>>(A, Bt, Cf, Cb, bias, resid,
                                             M, N, K, lda, ldb, ldc,
                                             aO, aI, bO, bI, cO, cI,
                                             ZH, scale, flags);
    };

    embed_k<<<2048, 256, 0, stream>>>(idx, tokW, posW, x);

    const long long TT = 1024ll * 1024;
    for (int l = 0; l < 6; l++) {
        const float* wq = Wq + (size_t)l * 1024 * 1024;
        const float* wk = Wk + (size_t)l * 1024 * 1024;
        const float* wv = Wv + (size_t)l * 1024 * 1024;
        const float* wo = Wo + (size_t)l * 1024 * 1024;
        const float* w1 = W1 + (size_t)l * 1024 * 4096;
        const float* w2 = W2 + (size_t)l * 4096 * 1024;

        dim3 tg(32, 32, 1);
        transpose_conv<<<tg, 256, 0, stream>>>(wq, wqkvT,            1024, 1024, 1024, 1024, 0, 0, 0);
        transpose_conv<<<tg, 256, 0, stream>>>(wk, wqkvT + 1048576,  1024, 1024, 1024, 1024, 0, 0, 0);
        transpose_conv<<<tg, 256, 0, stream>>>(wv, wqkvT + 2097152,  1024, 1024, 1024, 1024, 0, 0, 0);
        transpose_conv<<<tg, 256, 0, stream>>>(wo, woT,              1024, 1024, 1024, 1024, 0, 0, 0);
        transpose_conv<<<dim3(128, 32, 1), 256, 0, stream>>>(w1, w1T, 1024, 4096, 4096, 1024, 0, 0, 0);
        transpose_conv<<<dim3(32, 128, 1), 256, 0, stream>>>(w2, w2T, 4096, 1024, 1024, 4096, 0, 0, 0);

        // h = LN1(x)
        ln_k<<<2048, 256, 0, stream>>>(x, ln1g + l * 1024, ln1b + l * 1024, h);
        // qkv = h @ [Wq|Wk|Wv]
        gemm(h, wqkvT, nullptr, qkv, nullptr, nullptr,
             2048, 3072, 1024, 1024, 1024, 3072,
             0, 0, 0, 0, 0, 0, 1, 1, 1.f, 1);
        // vt[b, d, t] = V[b, t, d]
        transpose_conv<<<dim3(32, 32, 2), 256, 0, stream>>>(
            qkv + 2048, vt, 1024, 1024, 3072, 1024,
            1024ll * 3072, TT, 1);
        // S[b,h] = 1/8 * Q_h @ K_h^T   (z = b*16+h)
        gemm(qkv, qkv + 1024, nullptr, S, nullptr, nullptr,
             1024, 1024, 64, 3072, 3072, 1024,
             1024ll * 3072, 64, 1024ll * 3072, 64, 16 * TT, TT,
             32, 16, 0.125f, 1);
        softmax_causal<<<32768, 256, 0, stream>>>(S);
        // att[b,:,h*64..] = P @ V_h
        gemm(S, vt, nullptr, attb, nullptr, nullptr,
             1024, 64, 1024, 1024, 1024, 1024,
             16 * TT, TT, TT, 64ll * 1024, TT, 64,
             32, 16, 1.f, 1);
        // x = x + att @ Wo + bo
        gemm(attb, woT, x, nullptr, bo + l * 1024, x,
             2048, 1024, 1024, 1024, 1024, 1024,
             0, 0, 0, 0, 0, 0, 1, 1, 1.f, 0);
        // h = LN2(x)
        ln_k<<<2048, 256, 0, stream>>>(x, ln2g + l * 1024, ln2b + l * 1024, h);
        // ffb = gelu(h @ W1 + b1)
        gemm(h, w1T, nullptr, ffb, b1 + l * 4096, nullptr,
             2048, 4096, 1024, 1024, 1024, 4096,
             0, 0, 0, 0, 0, 0, 1, 1, 1.f, 1 | 2);
        // x = x + ffb @ W2 + b2
        gemm(ffb, w2T, x, nullptr, b2 + l * 1024, x,
             2048, 1024, 4096, 4096, 4096, 1024,
             0, 0, 0, 0, 0, 0, 1, 1, 1.f, 0);
    }

    // h = LNf(x); logits = h @ tok_W^T
    ln_k<<<2048, 256, 0, stream>>>(x, lnfg, lnfb, h);
    conv_f2b<<<50257, 256, 0, stream>>>(tokW, twb, 50257ull * 1024);
    gemm(h, twb, out, nullptr, nullptr, nullptr,
         2048, 50257, 1024, 1024, 1024, 50257,
         0, 0, 0, 0, 0, 0, 1, 1, 1.f, 0);
}

// Round 2
// 3155.240 us; speedup vs baseline: 1.1899x; 1.0435x over previous
//
#include <hip/hip_runtime.h>
#include <hip/hip_bf16.h>
#include <math.h>

// GPT forward: L=6, D=1024, H=16, HD=64, T=1024, B=2, V=50257
// All GEMMs: bf16 inputs, fp32 MFMA accumulate. Residual stream fp32.

using u16 = unsigned short;
typedef __attribute__((ext_vector_type(4))) float f32x4;
typedef __attribute__((ext_vector_type(8))) short s16x8;

static __device__ __forceinline__ u16 f2b(float f) {
    __hip_bfloat16 h = __float2bfloat16(f);
    return *reinterpret_cast<u16*>(&h);
}
static __device__ __forceinline__ float b2f(u16 u) {
    __hip_bfloat16 h = *reinterpret_cast<__hip_bfloat16*>(&u);
    return __bfloat162float(h);
}

// Async global->LDS, 16B per lane. LDS dest is wave-uniform base + lane*16.
#define GLDS16(gp, lp) __builtin_amdgcn_global_load_lds( \
    (const __attribute__((address_space(1))) unsigned int*)(gp), \
    (__attribute__((address_space(3))) unsigned int*)(lp), 16, 0, 0)

// ---------------------------------------------------------------------------
// Generic GEMM: C[M,N] = scale * A[M,K] @ B[K,N] (+bias) (+gelu) (+resid)
// A row-major bf16 (lda), Bt = B^T row-major bf16 [N,K] (ldb).
// z-batching: offsets = (z/ZH)*Outer + (z%ZH)*Inner for A, B, C.
// flags: 1 = bf16 output (Cb), else fp32 (Cf); 2 = exact GELU;
//        4 = dual-A mode: block covers TWO A slices (zh*2, zh*2+1); the
//            wn=0/1 wave column-halves use A slice 0/1 (for PV head pairs).
// Block tile 128x128, BK=32, 4 waves each 64x64 via 4x4 mfma 16x16x32.
// Grid: x = M-blocks (fast), y = N-blocks; XCD-aware bijective swizzle so
// each XCD's contiguous chunk covers all M-blocks of consecutive N-panels
// -> every B panel is fetched into exactly one XCD L2 (T1, m204 formula).
// Staging via global_load_lds width=16; ragged N handled by clamping the
// source row (duplicate reads; cols >= N never stored).
// ---------------------------------------------------------------------------
__global__ __launch_bounds__(256) void gemm_bt(
    const u16* __restrict__ A, const u16* __restrict__ Bt,
    float* __restrict__ Cf, u16* __restrict__ Cb,
    const float* __restrict__ bias, const float* __restrict__ resid,
    int M, int N, int K, int lda, int ldb, int ldc,
    long long aO, long long aI, long long bO, long long bI,
    long long cO, long long cI, int ZH, float scale, int flags)
{
    __shared__ u16 As[2 * 128 * 32];   // second tile used only in dual-A mode
    __shared__ u16 Bs[128 * 32];

    const int t = threadIdx.x;
    const int lane = t & 63, wave = t >> 6;
    const int wm = wave >> 1, wn = wave & 1;
    const int lr = lane & 15, lq = lane >> 4;

    // XCD-aware bijective swizzle over the x-y plane (x = M fast).
    const int gx = gridDim.x;
    const int nwg = gx * gridDim.y;
    const int orig = blockIdx.y * gx + blockIdx.x;
    const int qn = nwg >> 3, rn = nwg & 7;
    const int xcd = orig & 7, loc = orig >> 3;
    const int nid = (xcd < rn ? xcd * (qn + 1)
                              : rn * (qn + 1) + (xcd - rn) * qn) + loc;
    const int m0 = (nid % gx) * 128;
    const int n0 = (nid / gx) * 128;

    const bool dualA = (flags & 4) != 0;
    const int zb = blockIdx.z / ZH, zh = blockIdx.z % ZH;
    const long long offA = (long long)zb * aO
                         + (long long)(dualA ? 2 * zh : zh) * aI;
    const long long offB = (long long)zb * bO + (long long)zh * bI;
    const long long offC = (long long)zb * cO + (long long)zh * cI;

    f32x4 acc[4][4];
#pragma unroll
    for (int i = 0; i < 4; i++)
#pragma unroll
        for (int j = 0; j < 4; j++) acc[i][j] = (f32x4){0.f, 0.f, 0.f, 0.f};

    // staging map: thread t covers row r0 = t/4, k-chunk kk0 = (t%4)*8
    // -> LDS byte offset t*16 (linear), i.e. wave base = wave*1024.
    const int r0 = t >> 2;
    const int kk0 = (t & 3) << 3;
    const int wvb = wave << 10;

    // hoisted, strength-reduced staging pointers
    const u16* ap = A + offA + (size_t)(m0 + r0) * lda + kk0;
    const u16* apB = dualA ? (ap + aI) : ap;
    int nr  = n0 + r0;      if (nr  >= N) nr  = N - 1;
    int nr2 = n0 + r0 + 64; if (nr2 >= N) nr2 = N - 1;
    const u16* bp  = Bt + offB + (size_t)nr  * ldb + kk0;
    const u16* bp2 = Bt + offB + (size_t)nr2 * ldb + kk0;

    const u16* Asw = As + (dualA ? (wn * (128 * 32)) : 0);

    for (int k0 = 0; k0 < K; k0 += 32) {
        __syncthreads();
        GLDS16(ap,                      (char*)As + wvb);
        GLDS16(ap + (size_t)64 * lda,   (char*)As + 4096 + wvb);
        if (dualA) {
            GLDS16(apB,                    (char*)As + 8192 + wvb);
            GLDS16(apB + (size_t)64 * lda, (char*)As + 12288 + wvb);
        }
        GLDS16(bp,  (char*)Bs + wvb);
        GLDS16(bp2, (char*)Bs + 4096 + wvb);
        __syncthreads();

        s16x8 a[4], b[4];
#pragma unroll
        for (int i = 0; i < 4; i++)
            a[i] = *(const s16x8*)&Asw[(wm * 64 + i * 16 + lr) * 32 + lq * 8];
#pragma unroll
        for (int j = 0; j < 4; j++)
            b[j] = *(const s16x8*)&Bs[(wn * 64 + j * 16 + lr) * 32 + lq * 8];
#pragma unroll
        for (int i = 0; i < 4; i++)
#pragma unroll
            for (int j = 0; j < 4; j++)
                acc[i][j] = __builtin_amdgcn_mfma_f32_16x16x32_bf16(
                    a[i], b[j], acc[i][j], 0, 0, 0);

        ap += 32; apB += 32; bp += 32; bp2 += 32;
    }

    const bool obf = (flags & 1) != 0;
    const bool gel = (flags & 2) != 0;
#pragma unroll
    for (int i = 0; i < 4; i++) {
#pragma unroll
        for (int j = 0; j < 4; j++) {
            int col = n0 + wn * 64 + j * 16 + lr;
            if (col >= N) continue;
#pragma unroll
            for (int r = 0; r < 4; r++) {
                int row = m0 + wm * 64 + i * 16 + lq * 4 + r;
                float v = acc[i][j][r] * scale;
                if (bias) v += bias[col];
                if (gel) v = 0.5f * v * (1.f + erff(v * 0.70710678118f));
                long long ci = offC + (long long)row * ldc + col;
                if (resid) v += resid[ci];
                if (obf) Cb[ci] = f2b(v);
                else     Cf[ci] = v;
            }
        }
    }
}

// ---------------------------------------------------------------------------
// Transpose + convert to bf16: out[c*ldo + r] = in[r*ldi + c]. R,C mult of 32.
// ---------------------------------------------------------------------------
__global__ __launch_bounds__(256) void transpose_conv(
    const void* __restrict__ in, u16* __restrict__ out,
    int R, int C, int ldi, int ldo, long long zi, long long zo, int in_bf16)
{
    __shared__ float tile[32][33];
    int tx = threadIdx.x & 31, ty = threadIdx.x >> 5;  // 32x8
    int r0 = blockIdx.y * 32, c0 = blockIdx.x * 32;
    long long ioff = (long long)blockIdx.z * zi;
    long long ooff = (long long)blockIdx.z * zo;
#pragma unroll
    for (int i = 0; i < 32; i += 8) {
        long long r = r0 + ty + i, c = c0 + tx;
        float v;
        if (in_bf16) v = b2f(((const u16*)in)[ioff + r * ldi + c]);
        else         v = ((const float*)in)[ioff + r * ldi + c];
        tile[ty + i][tx] = v;
    }
    __syncthreads();
#pragma unroll
    for (int i = 0; i < 32; i += 8) {
        long long c = c0 + ty + i, r = r0 + tx;
        out[ooff + c * ldo + r] = f2b(tile[tx][ty + i]);
    }
}

// flat fp32 -> bf16 (n multiple of 4)
__global__ __launch_bounds__(256) void conv_f2b(
    const float* __restrict__ in, u16* __restrict__ out, size_t n)
{
    size_t i = ((size_t)blockIdx.x * 256 + threadIdx.x) * 4;
    if (i >= n) return;
    float4 f = *(const float4*)&in[i];
    out[i + 0] = f2b(f.x);
    out[i + 1] = f2b(f.y);
    out[i + 2] = f2b(f.z);
    out[i + 3] = f2b(f.w);
}

// x[row,:] = tok_W[idx[row],:] + pos_W[row&1023,:]
__global__ __launch_bounds__(256) void embed_k(
    const int* __restrict__ idx, const float* __restrict__ tokW,
    const float* __restrict__ posW, float* __restrict__ x)
{
    int row = blockIdx.x;
    int tt = row & 1023;
    int tok = idx[row];
    int c = threadIdx.x * 4;
    float4 a = *(const float4*)&tokW[(size_t)tok * 1024 + c];
    float4 p = *(const float4*)&posW[(size_t)tt * 1024 + c];
    float4 r = {a.x + p.x, a.y + p.y, a.z + p.z, a.w + p.w};
    *(float4*)&x[(size_t)row * 1024 + c] = r;
}

// LayerNorm over D=1024, fp32 in, bf16 out. One block per row.
__global__ __launch_bounds__(256) void ln_k(
    const float* __restrict__ x, const float* __restrict__ g,
    const float* __restrict__ b, u16* __restrict__ out)
{
    __shared__ float sbuf[8];
    int row = blockIdx.x;
    int c = threadIdx.x * 4;
    float4 v = *(const float4*)&x[(size_t)row * 1024 + c];
    float s = v.x + v.y + v.z + v.w;
    float s2 = v.x * v.x + v.y * v.y + v.z * v.z + v.w * v.w;
#pragma unroll
    for (int o = 32; o > 0; o >>= 1) {
        s += __shfl_down(s, o, 64);
        s2 += __shfl_down(s2, o, 64);
    }
    int lane = threadIdx.x & 63, wave = threadIdx.x >> 6;
    if (lane == 0) { sbuf[wave] = s; sbuf[4 + wave] = s2; }
    __syncthreads();
    float mean = (sbuf[0] + sbuf[1] + sbuf[2] + sbuf[3]) * (1.f / 1024.f);
    float m2 = (sbuf[4] + sbuf[5] + sbuf[6] + sbuf[7]) * (1.f / 1024.f);
    float rstd = rsqrtf(m2 - mean * mean + 1e-5f);
    float vals[4] = {v.x, v.y, v.z, v.w};
    u16 o4[4];
#pragma unroll
    for (int i = 0; i < 4; i++) {
        float y = (vals[i] - mean) * rstd * g[c + i] + b[c + i];
        o4[i] = f2b(y);
    }
    *(uint2*)&out[(size_t)row * 1024 + c] = *(uint2*)o4;
}

// Causal softmax over rows of S [32*1024, 1024] bf16, in-place -> P.
// row = bh*1024 + q; valid keys k <= q; invalid entries written as 0.
__global__ __launch_bounds__(256) void softmax_causal(u16* __restrict__ S)
{
    __shared__ float sbuf[8];
    int row = blockIdx.x;
    int q = row & 1023;
    u16* p = S + (size_t)row * 1024;
    int c = threadIdx.x * 4;
    u16 u4[4];
    *(uint2*)u4 = *(const uint2*)&p[c];
    float v[4];
#pragma unroll
    for (int i = 0; i < 4; i++) v[i] = (c + i <= q) ? b2f(u4[i]) : -1e30f;
    float mx = fmaxf(fmaxf(v[0], v[1]), fmaxf(v[2], v[3]));
#pragma unroll
    for (int o = 32; o > 0; o >>= 1) mx = fmaxf(mx, __shfl_down(mx, o, 64));
    int lane = threadIdx.x & 63, wave = threadIdx.x >> 6;
    if (lane == 0) sbuf[wave] = mx;
    __syncthreads();
    mx = fmaxf(fmaxf(sbuf[0], sbuf[1]), fmaxf(sbuf[2], sbuf[3]));
    float e[4], sum = 0.f;
#pragma unroll
    for (int i = 0; i < 4; i++) {
        e[i] = (c + i <= q) ? expf(v[i] - mx) : 0.f;
        sum += e[i];
    }
#pragma unroll
    for (int o = 32; o > 0; o >>= 1) sum += __shfl_down(sum, o, 64);
    if (lane == 0) sbuf[4 + wave] = sum;
    __syncthreads();
    float inv = 1.f / (sbuf[4] + sbuf[5] + sbuf[6] + sbuf[7]);
#pragma unroll
    for (int i = 0; i < 4; i++) u4[i] = f2b(e[i] * inv);
    *(uint2*)&p[c] = *(uint2*)u4;
}

// ---------------------------------------------------------------------------
extern "C" void kernel_launch(void* const* d_in, const int* in_sizes, int n_in,
                              void* d_out, int out_size, void* d_ws, size_t ws_size,
                              hipStream_t stream)
{
    const int*   idx  = (const int*)d_in[0];
    const float* tokW = (const float*)d_in[1];
    const float* posW = (const float*)d_in[2];
    const float* ln1g = (const float*)d_in[3];
    const float* ln1b = (const float*)d_in[4];
    const float* Wq   = (const float*)d_in[5];
    const float* Wk   = (const float*)d_in[6];
    const float* Wv   = (const float*)d_in[7];
    const float* Wo   = (const float*)d_in[8];
    const float* bo   = (const float*)d_in[9];
    const float* ln2g = (const float*)d_in[10];
    const float* ln2b = (const float*)d_in[11];
    const float* W1   = (const float*)d_in[12];
    const float* b1   = (const float*)d_in[13];
    const float* W2   = (const float*)d_in[14];
    const float* b2   = (const float*)d_in[15];
    const float* lnfg = (const float*)d_in[16];
    const float* lnfb = (const float*)d_in[17];
    float* out = (float*)d_out;

    char* w = (char*)d_ws;
    auto alloc = [&](size_t bytes) -> char* {
        char* p = w;
        w += (bytes + 255) & ~(size_t)255;
        return p;
    };
    float* x    = (float*)alloc(2048ull * 1024 * 4);   // residual stream fp32
    u16* h      = (u16*)alloc(2048ull * 1024 * 2);     // LN out bf16
    u16* qkv    = (u16*)alloc(2048ull * 3072 * 2);     // fused QKV out
    u16* vt     = (u16*)alloc(2ull * 1024 * 1024 * 2); // V transposed per batch
    u16* attb   = (u16*)alloc(2048ull * 1024 * 2);     // attention out bf16
    u16* ffb    = (u16*)alloc(2048ull * 4096 * 2);     // FF hidden bf16
    u16* wqkvT  = (u16*)alloc(3072ull * 1024 * 2);     // per-layer Wqkv^T bf16
    u16* woT    = (u16*)alloc(1024ull * 1024 * 2);
    u16* w1T    = (u16*)alloc(4096ull * 1024 * 2);
    u16* w2T    = (u16*)alloc(1024ull * 4096 * 2);
    u16* S      = (u16*)alloc(50257ull * 1024 * 2);    // scores/P; reused as tok_W bf16
    u16* twb    = S;

    auto gemm = [&](const u16* A, const u16* Bt, float* Cf, u16* Cb,
                    const float* bias, const float* resid,
                    int M, int N, int K, int lda, int ldb, int ldc,
                    long long aO, long long aI, long long bO, long long bI,
                    long long cO, long long cI, int Z, int ZH,
                    float scale, int flags) {
        // x = M-blocks (fast-varying), y = N-blocks -> column-major dispatch
        dim3 g(M / 128, (N + 127) / 128, Z);
        gemm_bt<<<g, dim3(256), 0, stream>>>(A, Bt, Cf, Cb, bias, resid,
                                             M, N, K, lda, ldb, ldc,
                                             aO, aI, bO, bI, cO, cI,
                                             ZH, scale, flags);
    };

    embed_k<<<2048, 256, 0, stream>>>(idx, tokW, posW, x);

    const long long TT = 1024ll * 1024;
    for (int l = 0; l < 6; l++) {
        const float* wq = Wq + (size_t)l * 1024 * 1024;
        const float* wk = Wk + (size_t)l * 1024 * 1024;
        const float* wv = Wv + (size_t)l * 1024 * 1024;
        const float* wo = Wo + (size_t)l * 1024 * 1024;
        const float* w1 = W1 + (size_t)l * 1024 * 4096;
        const float* w2 = W2 + (size_t)l * 4096 * 1024;

        dim3 tg(32, 32, 1);
        transpose_conv<<<tg, 256, 0, stream>>>(wq, wqkvT,            1024, 1024, 1024, 1024, 0, 0, 0);
        transpose_conv<<<tg, 256, 0, stream>>>(wk, wqkvT + 1048576,  1024, 1024, 1024, 1024, 0, 0, 0);
        transpose_conv<<<tg, 256, 0, stream>>>(wv, wqkvT + 2097152,  1024, 1024, 1024, 1024, 0, 0, 0);
        transpose_conv<<<tg, 256, 0, stream>>>(wo, woT,              1024, 1024, 1024, 1024, 0, 0, 0);
        transpose_conv<<<dim3(128, 32, 1), 256, 0, stream>>>(w1, w1T, 1024, 4096, 4096, 1024, 0, 0, 0);
        transpose_conv<<<dim3(32, 128, 1), 256, 0, stream>>>(w2, w2T, 4096, 1024, 1024, 4096, 0, 0, 0);

        // h = LN1(x)
        ln_k<<<2048, 256, 0, stream>>>(x, ln1g + l * 1024, ln1b + l * 1024, h);
        // qkv = h @ [Wq|Wk|Wv]
        gemm(h, wqkvT, nullptr, qkv, nullptr, nullptr,
             2048, 3072, 1024, 1024, 1024, 3072,
             0, 0, 0, 0, 0, 0, 1, 1, 1.f, 1);
        // vt[b, d, t] = V[b, t, d]
        transpose_conv<<<dim3(32, 32, 2), 256, 0, stream>>>(
            qkv + 2048, vt, 1024, 1024, 3072, 1024,
            1024ll * 3072, TT, 1);
        // S[b,h] = 1/8 * Q_h @ K_h^T   (z = b*16+h)
        gemm(qkv, qkv + 1024, nullptr, S, nullptr, nullptr,
             1024, 1024, 64, 3072, 3072, 1024,
             1024ll * 3072, 64, 1024ll * 3072, 64, 16 * TT, TT,
             32, 16, 0.125f, 1);
        softmax_causal<<<32768, 256, 0, stream>>>(S);
        // att[b,:,pair*128..] = [P_h0 @ V_h0 | P_h1 @ V_h1]  (dual-A, z = b*8+pair)
        gemm(S, vt, nullptr, attb, nullptr, nullptr,
             1024, 128, 1024, 1024, 1024, 1024,
             16 * TT, TT, TT, 128ll * 1024, TT, 128,
             16, 8, 1.f, 1 | 4);
        // x = x + att @ Wo + bo
        gemm(attb, woT, x, nullptr, bo + l * 1024, x,
             2048, 1024, 1024, 1024, 1024, 1024,
             0, 0, 0, 0, 0, 0, 1, 1, 1.f, 0);
        // h = LN2(x)
        ln_k<<<2048, 256, 0, stream>>>(x, ln2g + l * 1024, ln2b + l * 1024, h);
        // ffb = gelu(h @ W1 + b1)
        gemm(h, w1T, nullptr, ffb, b1 + l * 4096, nullptr,
             2048, 4096, 1024, 1024, 1024, 4096,
             0, 0, 0, 0, 0, 0, 1, 1, 1.f, 1 | 2);
        // x = x + ffb @ W2 + b2
        gemm(ffb, w2T, x, nullptr, b2 + l * 1024, x,
             2048, 1024, 4096, 4096, 4096, 1024,
             0, 0, 0, 0, 0, 0, 1, 1, 1.f, 0);
    }

    // h = LNf(x); logits = h @ tok_W^T
    ln_k<<<2048, 256, 0, stream>>>(x, lnfg, lnfb, h);
    conv_f2b<<<50257, 256, 0, stream>>>(tokW, twb, 50257ull * 1024);
    gemm(h, twb, out, nullptr, nullptr, nullptr,
         2048, 50257, 1024, 1024, 1024, 50257,
         0, 0, 0, 0, 0, 0, 1, 1, 1.f, 0);
}